// Round 6
// baseline (421.967 us; speedup 1.0000x reference)
//
#include <hip/hip_runtime.h>
#include <math.h>

// CapsNet fused forward, v6: one d-slice per block (32KB c1t -> 4 blocks/CU),
// fused epilogue via completion counter.
// pre : conv1_w -> c1wp2[256][96] bf16 (K-permuted); prim_w -> pw2[85][32o][32i]
//       bf16 (taps 81..84 zero); colsum(dig_Wb); OW=sum_i out_w; S=0; done=0.
// main: one block (256 thr = 4 waves) per (image, d). conv1 mt strided 4 over
//       waves; prim taps strided 4 over waves, A-frags prefetched, B-frag =
//       ds_read_b128 from skewed c1t. 4-wave tap reduction; waves 0,1 fold
//       u*dig_W (m-tiles 0/1), atomicAdd S. Last block computes epilogue.

typedef __attribute__((ext_vector_type(8))) short bf16x8;
typedef __attribute__((ext_vector_type(4))) float f32x4;

__device__ inline unsigned short f2bf(float f) {
    union { float f; unsigned u; } v; v.f = f;
    unsigned r = v.u + 0x7fff + ((v.u >> 16) & 1);   // RNE
    return (unsigned short)(r >> 16);
}

#define C1TN 16008   // u16 per c1t slice (400*40 + 8 skew pad)

// ---------------- pre kernel ----------------
__global__ void caps_pre(const float* __restrict__ conv1_w,
                         const float* __restrict__ prim_w,
                         const float* __restrict__ dig_Wb,
                         const float* __restrict__ out_w,
                         float* __restrict__ S,              // [B*16]
                         float* __restrict__ colsum,         // [16]
                         float* __restrict__ OW,             // [160]
                         unsigned* __restrict__ done,        // [1]
                         unsigned short* __restrict__ c1wp2, // [256*96]
                         unsigned short* __restrict__ pw2,   // [85*1024]
                         int B)
{
    const int t = threadIdx.x;
    if (blockIdx.x == 468) {
        __shared__ float cs[16];
        if (t < 16) cs[t] = 0.f;
        if (t == 255) *done = 0u;
        __syncthreads();
        {
            const int k = t & 15, g = t >> 4;
            float s = 0.f;
            for (int j = 0; j < 72; ++j) s += dig_Wb[(g * 72 + j) * 16 + k];
            atomicAdd(&cs[k], s);
        }
        __syncthreads();
        if (t < 16) colsum[t] = cs[t];
        if (t >= 64 && t < 224) {
            const int idx = t - 64, o = idx >> 4, k = idx & 15;
            float s = 0.f;
            for (int i = 0; i < 10; ++i) s += out_w[(o * 10 + i) * 16 + k];
            OW[idx] = s;
        }
        return;
    }
    const int tid = blockIdx.x * 256 + t;
    if (tid < 24576) {                       // c1wp2, K-permuted
        const int c = tid / 96, kn = tid % 96;
        unsigned short v = 0;
        if (kn < 72) {
            const int p = kn >> 1, lo = kn & 1, ky = p >> 2, kx = 2 * (p & 3) + lo;
            v = f2bf(conv1_w[c * 81 + 9 * ky + kx]);
        } else if (kn < 81) {
            v = f2bf(conv1_w[c * 81 + 9 * (kn - 72) + 8]);
        }
        c1wp2[tid] = v;
    } else if (tid < 107520) {               // pw2: coalesced read, scattered write
        const int j = tid - 24576;           // j = row*81 + tap, row = o*32+i
        const int row = j / 81, tap = j - 81 * row;
        pw2[tap * 1024 + row] = f2bf(prim_w[j]);
    } else if (tid < 111616) {               // zero taps 81..84
        pw2[81 * 1024 + (tid - 107520)] = 0;
    } else {                                 // S = 0
        const int k = tid - 111616;
        if (k < B * 16) S[k] = 0.f;
    }
}

// ---------------- main kernel ----------------
__global__ __launch_bounds__(256, 4) void caps_main(
    const float* __restrict__ x,
    const float* __restrict__ conv1_b,
    const float* __restrict__ prim_b,
    const float* __restrict__ dig_W,
    const unsigned short* __restrict__ c1wp2,
    const unsigned short* __restrict__ pw2,
    float* __restrict__ S,
    const float* __restrict__ colsum,
    const float* __restrict__ OW,
    const float* __restrict__ out_b,
    unsigned* __restrict__ done,
    float* __restrict__ out,
    int nblocks)
{
    __shared__ __align__(16) unsigned short c1t[C1TN];      // 32 KB (1 d-slice)
    __shared__ __align__(16) unsigned imgp[1344];           // bf16 pairs + zero pad
    __shared__ unsigned short offT[64];                     // byte offsets into imgp
    __shared__ float pbs[32];
    __shared__ int lastflag;

    const int b = blockIdx.x >> 3, d = blockIdx.x & 7;
    const int t = threadIdx.x;
    const int wave = t >> 6, lane = t & 63, quad = lane >> 4, l16 = lane & 15;

    // ---- imgp: packed bf16 pairs (img[y][x], img[y][x+1]), zero pad to 1344 ----
    const float* xb = x + b * 784;
    for (int j = t; j < 1344; j += 256) {
        unsigned v = 0;
        if (j < 784) {
            const float a = xb[j];
            const int xc = j - 28 * (int)(((unsigned)j * 37450u) >> 20);
            const float c = (xc < 27) ? xb[j + 1] : 0.f;
            v = (unsigned)f2bf(a) | ((unsigned)f2bf(c) << 16);
        }
        imgp[j] = v;
    }
    // ---- tap-offset tables (byte offsets, x4) ----
    if (t < 64) {
        int v;
        if (t < 32) {
            const int ky = t >> 2, kx = 2 * (t & 3);
            v = ky * 28 + kx;
        } else {
            const int k = t + 32;
            if (k < 72) {
                const int p = k >> 1, lo = k & 1, ky = p >> 2, kx = 2 * (p & 3) + lo;
                v = ky * 28 + kx;
            } else if (k < 81) {
                v = (k - 72) * 28 + 8;
            } else v = 784;
        }
        offT[t] = (unsigned short)(4 * v);
    }
    if (t < 32) pbs[t] = prim_b[t];
    if (t == 0) lastflag = 0;
    __syncthreads();

    // hoist per-lane tap byte-offsets
    unsigned tp0[4], tp1[4], t2a[4], t2b[4];
#pragma unroll
    for (int r = 0; r < 4; ++r) {
        tp0[r] = offT[quad * 4 + r];
        tp1[r] = offT[16 + quad * 4 + r];
        t2a[r] = offT[32 + quad * 8 + 2 * r];
        t2b[r] = offT[32 + quad * 8 + 2 * r + 1];
    }

    // ======== conv1: mt strided 4 across waves ========
    {
        const float cb0 = conv1_b[l16 * 8 + d];
        const float cb1 = conv1_b[(16 + l16) * 8 + d];
        bf16x8 Bw0[3], Bw1[3];
#pragma unroll
        for (int ks = 0; ks < 3; ++ks) {
            Bw0[ks] = *(const bf16x8*)&c1wp2[(l16 * 8 + d) * 96 + ks * 32 + quad * 8];
            Bw1[ks] = *(const bf16x8*)&c1wp2[((16 + l16) * 8 + d) * 96 + ks * 32 + quad * 8];
        }
        for (int mt = wave; mt < 25; mt += 4) {
            const int pos = mt * 16 + l16;
            const int y = (int)(((unsigned)pos * 52429u) >> 20);
            const unsigned pb4 = (unsigned)(pos + 8 * y) * 4u;   // 4*(y*28+x)
            f32x4 a0 = {0.f, 0.f, 0.f, 0.f}, a1 = {0.f, 0.f, 0.f, 0.f};
            union { unsigned u[4]; bf16x8 v; } A;
#pragma unroll
            for (int r = 0; r < 4; ++r)
                A.u[r] = *(const unsigned*)((const char*)imgp + (pb4 + tp0[r]));
            a0 = __builtin_amdgcn_mfma_f32_16x16x32_bf16(A.v, Bw0[0], a0, 0, 0, 0);
            a1 = __builtin_amdgcn_mfma_f32_16x16x32_bf16(A.v, Bw1[0], a1, 0, 0, 0);
#pragma unroll
            for (int r = 0; r < 4; ++r)
                A.u[r] = *(const unsigned*)((const char*)imgp + (pb4 + tp1[r]));
            a0 = __builtin_amdgcn_mfma_f32_16x16x32_bf16(A.v, Bw0[1], a0, 0, 0, 0);
            a1 = __builtin_amdgcn_mfma_f32_16x16x32_bf16(A.v, Bw1[1], a1, 0, 0, 0);
#pragma unroll
            for (int r = 0; r < 4; ++r) {
                const unsigned lo = *(const unsigned*)((const char*)imgp + (pb4 + t2a[r]));
                const unsigned hi = *(const unsigned*)((const char*)imgp + (pb4 + t2b[r]));
                A.u[r] = (lo & 0xFFFFu) | (hi << 16);
            }
            a0 = __builtin_amdgcn_mfma_f32_16x16x32_bf16(A.v, Bw0[2], a0, 0, 0, 0);
            a1 = __builtin_amdgcn_mfma_f32_16x16x32_bf16(A.v, Bw1[2], a1, 0, 0, 0);
#pragma unroll
            for (int r = 0; r < 4; ++r) {
                const int pr = mt * 16 + quad * 4 + r;
                const int spar = (int)((((unsigned)pr * 52429u) >> 21) & 1u);
                const int base = pr * 40 + 8 * spar;
                c1t[base + l16]      = f2bf(fmaxf(a0[r] + cb0, 0.f));
                c1t[base + 16 + l16] = f2bf(fmaxf(a1[r] + cb1, 0.f));
            }
        }
    }
    __syncthreads();

    // ======== prim GEMM: K=32 ch per tap, 81 taps strided 4 across waves ======
    const int hp = l16 >> 3, wp = l16 & 7;               // n = 8h' + w'
    const unsigned Lbase = 80u * (unsigned)(40 * hp + 2 * wp) + 16u * quad;
    const unsigned Lh0 = Lbase + 16u * hp;               // kk=0: spar=hp
    const unsigned Lh1 = Lbase + 16u * (1 - hp);         // kk=1: spar=1-hp

    f32x4 pa[6];
#pragma unroll
    for (int q = 0; q < 6; ++q) pa[q] = (f32x4){0.f, 0.f, 0.f, 0.f};

    {
        const unsigned short* apbase = pw2 + l16 * 32 + quad * 8;
        int off = wave;
        bf16x8 A0 = *(const bf16x8*)(apbase + off * 1024);
        bf16x8 A1 = *(const bf16x8*)(apbase + off * 1024 + 512);
        for (; off < 81; off += 4) {
            const int noff = off + 4;                    // <= 84: pw2 zero-padded
            const bf16x8 nA0 = *(const bf16x8*)(apbase + noff * 1024);
            const bf16x8 nA1 = *(const bf16x8*)(apbase + noff * 1024 + 512);
            const int ky = (off * 57) >> 9;
            const int kx = off - 9 * ky;
            const int kk = (ky >> 1) & 1;
            const unsigned soff = 80u * (unsigned)(20 * ky + kx);
            const unsigned ad = (kk ? Lh1 : Lh0) + soff;
            const char* b0 = (const char*)c1t + ad;
#pragma unroll
            for (int nt = 0; nt < 3; ++nt) {
                const bf16x8 Bf0 = *(const bf16x8*)(b0 + nt * 6400);
                pa[nt]     = __builtin_amdgcn_mfma_f32_16x16x32_bf16(A0, Bf0, pa[nt],     0, 0, 0);
                pa[3 + nt] = __builtin_amdgcn_mfma_f32_16x16x32_bf16(A1, Bf0, pa[3 + nt], 0, 0, 0);
            }
            A0 = nA0; A1 = nA1;
        }
    }
    __syncthreads();

    // ---- 4-wave tap reduction (redbuf overlays c1t) ----
    f32x4* redbuf = (f32x4*)c1t;
    if (wave >= 2) {
#pragma unroll
        for (int q = 0; q < 6; ++q) redbuf[((wave - 2) * 6 + q) * 64 + lane] = pa[q];
    }
    __syncthreads();
    if (wave < 2) {
#pragma unroll
        for (int q = 0; q < 6; ++q) pa[q] += redbuf[(wave * 6 + q) * 64 + lane];
        if (wave == 0) {               // export mt1 half
#pragma unroll
            for (int q = 0; q < 3; ++q) redbuf[(12 + q) * 64 + lane] = pa[3 + q];
        } else {                       // export mt0 half
#pragma unroll
            for (int q = 0; q < 3; ++q) redbuf[(15 + q) * 64 + lane] = pa[q];
        }
    }
    __syncthreads();

    if (wave < 2) {
        f32x4 full[3];
#pragma unroll
        for (int q = 0; q < 3; ++q)
            full[q] = (wave == 0) ? (pa[q] + redbuf[(15 + q) * 64 + lane])
                                  : (pa[3 + q] + redbuf[(12 + q) * 64 + lane]);

        // ---- ReLU + fold u * dig_W (wave = m-tile) ----
        float part[16];
#pragma unroll
        for (int k = 0; k < 16; ++k) part[k] = 0.f;

        if (wp < 6) {
#pragma unroll
            for (int nt = 0; nt < 3; ++nt) {
                const f32x4 u4 = full[nt];
                const int h = 2 * nt + hp;
#pragma unroll
                for (int r = 0; r < 4; ++r) {
                    const int o = wave * 16 + quad * 4 + r;
                    const float val = fmaxf(u4[r] + pbs[o], 0.f);
                    const int nc = o * 36 + wp * 6 + h;
                    const f32x4* wd = (const f32x4*)&dig_W[(nc * 8 + d) * 16];
#pragma unroll
                    for (int m = 0; m < 4; ++m) {
                        const f32x4 wv = wd[m];
                        part[m * 4 + 0] = fmaf(val, wv[0], part[m * 4 + 0]);
                        part[m * 4 + 1] = fmaf(val, wv[1], part[m * 4 + 1]);
                        part[m * 4 + 2] = fmaf(val, wv[2], part[m * 4 + 2]);
                        part[m * 4 + 3] = fmaf(val, wv[3], part[m * 4 + 3]);
                    }
                }
            }
        }

#pragma unroll
        for (int k = 0; k < 16; ++k) {
            float v = part[k];
            v += __shfl_xor(v, 32, 64);
            v += __shfl_xor(v, 16, 64);
            v += __shfl_xor(v, 8, 64);
            v += __shfl_xor(v, 4, 64);
            v += __shfl_xor(v, 2, 64);
            v += __shfl_xor(v, 1, 64);
            part[k] = v;
        }
        if (lane == 0) {
#pragma unroll
            for (int k = 0; k < 16; ++k) atomicAdd(&S[b * 16 + k], part[k]);
            __threadfence();           // make S-adds device-visible (release)
        }
    }
    __syncthreads();

    // ---- completion counter: last block runs the epilogue for all images ----
    if (t == 0) {
        const unsigned old = atomicAdd(done, 1u);
        lastflag = (old == (unsigned)(nblocks - 1)) ? 1 : 0;
    }
    __syncthreads();
    if (lastflag) {
        __threadfence();               // acquire: see all other blocks' S
        for (int bb = t; bb < 512; bb += 256) {
            float Sv[16]; float l2 = 0.f, l1 = 0.f;
#pragma unroll
            for (int k = 0; k < 16; ++k) {
                const float s = (S[bb * 16 + k] + colsum[k]) * (1.f / 1152.f);
                Sv[k] = s; l2 += s * s; l1 += fabsf(s);
            }
            l2 = sqrtf(l2);
            const float sc = l2 / (1.f + l2) / l1;
            float lg[10]; float mx = -1e30f;
#pragma unroll
            for (int o = 0; o < 10; ++o) {
                float a = out_b[o];
#pragma unroll
                for (int k = 0; k < 16; ++k) a = fmaf(Sv[k] * sc, OW[o * 16 + k], a);
                lg[o] = a; mx = fmaxf(mx, a);
            }
            float sum = 0.f;
#pragma unroll
            for (int o = 0; o < 10; ++o) { lg[o] = expf(lg[o] - mx); sum += lg[o]; }
            const float inv = 1.f / sum;
#pragma unroll
            for (int o = 0; o < 10; ++o) out[bb * 10 + o] = lg[o] * inv;
        }
    }
}

extern "C" void kernel_launch(void* const* d_in, const int* in_sizes, int n_in,
                              void* d_out, int out_size, void* d_ws, size_t ws_size,
                              hipStream_t stream) {
    const float* x       = (const float*)d_in[0];
    const float* conv1_w = (const float*)d_in[1];
    const float* conv1_b = (const float*)d_in[2];
    const float* prim_w  = (const float*)d_in[3];
    const float* prim_b  = (const float*)d_in[4];
    const float* dig_W   = (const float*)d_in[5];
    const float* dig_Wb  = (const float*)d_in[6];
    const float* out_w   = (const float*)d_in[7];
    const float* out_b   = (const float*)d_in[8];
    float* out = (float*)d_out;

    const int B = in_sizes[0] / 784;   // 512

    char* w = (char*)d_ws;
    float* S              = (float*)(w);                 // 32768 B
    float* colsum         = (float*)(w + 32768);         // 64 B
    float* OW             = (float*)(w + 32832);         // 640 B
    unsigned* done        = (unsigned*)(w + 33472);      // 64 B slot
    unsigned short* c1wp2 = (unsigned short*)(w + 33536);            // 49152 B
    unsigned short* pw2   = (unsigned short*)(w + 33536 + 49152);    // 174080 B

    const int nblocks = B * 8;
    caps_pre<<<469, 256, 0, stream>>>(conv1_w, prim_w, dig_Wb, out_w,
                                      S, colsum, OW, done, c1wp2, pw2, B);
    caps_main<<<nblocks, 256, 0, stream>>>(x, conv1_b, prim_b, dig_W, c1wp2, pw2,
                                           S, colsum, OW, out_b, done, out, nblocks);
}

// Round 7
// 367.988 us; speedup vs baseline: 1.1467x; 1.1467x over previous
//
#include <hip/hip_runtime.h>
#include <math.h>

// CapsNet fused forward, v7: v6 structure (one d-slice/block, 32KB c1t,
// fused epilogue) with launch_bounds(256,2) so the allocator does NOT
// crush VGPRs to 64 and spill (v6 failure: VGPR=64, 33MB scratch writes).
// LDS 37.9KB -> 4 blocks/CU; expect ~124 VGPR -> 4 waves/EU -> 16 waves/CU.

typedef __attribute__((ext_vector_type(8))) short bf16x8;
typedef __attribute__((ext_vector_type(4))) float f32x4;

__device__ inline unsigned short f2bf(float f) {
    union { float f; unsigned u; } v; v.f = f;
    unsigned r = v.u + 0x7fff + ((v.u >> 16) & 1);   // RNE
    return (unsigned short)(r >> 16);
}

#define C1TN 16008   // u16 per c1t slice (400*40 + 8 skew pad)

// ---------------- pre kernel ----------------
__global__ void caps_pre(const float* __restrict__ conv1_w,
                         const float* __restrict__ prim_w,
                         const float* __restrict__ dig_Wb,
                         const float* __restrict__ out_w,
                         float* __restrict__ S,              // [B*16]
                         float* __restrict__ colsum,         // [16]
                         float* __restrict__ OW,             // [160]
                         unsigned* __restrict__ done,        // [1]
                         unsigned short* __restrict__ c1wp2, // [256*96]
                         unsigned short* __restrict__ pw2,   // [85*1024]
                         int B)
{
    const int t = threadIdx.x;
    if (blockIdx.x == 468) {
        __shared__ float cs[16];
        if (t < 16) cs[t] = 0.f;
        if (t == 255) *done = 0u;
        __syncthreads();
        {
            const int k = t & 15, g = t >> 4;
            float s = 0.f;
            for (int j = 0; j < 72; ++j) s += dig_Wb[(g * 72 + j) * 16 + k];
            atomicAdd(&cs[k], s);
        }
        __syncthreads();
        if (t < 16) colsum[t] = cs[t];
        if (t >= 64 && t < 224) {
            const int idx = t - 64, o = idx >> 4, k = idx & 15;
            float s = 0.f;
            for (int i = 0; i < 10; ++i) s += out_w[(o * 10 + i) * 16 + k];
            OW[idx] = s;
        }
        return;
    }
    const int tid = blockIdx.x * 256 + t;
    if (tid < 24576) {                       // c1wp2, K-permuted
        const int c = tid / 96, kn = tid % 96;
        unsigned short v = 0;
        if (kn < 72) {
            const int p = kn >> 1, lo = kn & 1, ky = p >> 2, kx = 2 * (p & 3) + lo;
            v = f2bf(conv1_w[c * 81 + 9 * ky + kx]);
        } else if (kn < 81) {
            v = f2bf(conv1_w[c * 81 + 9 * (kn - 72) + 8]);
        }
        c1wp2[tid] = v;
    } else if (tid < 107520) {               // pw2: coalesced read, scattered write
        const int j = tid - 24576;           // j = row*81 + tap, row = o*32+i
        const int row = j / 81, tap = j - 81 * row;
        pw2[tap * 1024 + row] = f2bf(prim_w[j]);
    } else if (tid < 111616) {               // zero taps 81..84
        pw2[81 * 1024 + (tid - 107520)] = 0;
    } else {                                 // S = 0
        const int k = tid - 111616;
        if (k < B * 16) S[k] = 0.f;
    }
}

// ---------------- main kernel ----------------
__global__ __launch_bounds__(256, 2) void caps_main(
    const float* __restrict__ x,
    const float* __restrict__ conv1_b,
    const float* __restrict__ prim_b,
    const float* __restrict__ dig_W,
    const unsigned short* __restrict__ c1wp2,
    const unsigned short* __restrict__ pw2,
    float* __restrict__ S,
    const float* __restrict__ colsum,
    const float* __restrict__ OW,
    const float* __restrict__ out_b,
    unsigned* __restrict__ done,
    float* __restrict__ out,
    int nblocks)
{
    __shared__ __align__(16) unsigned short c1t[C1TN];      // 32 KB (1 d-slice)
    __shared__ __align__(16) unsigned imgp[1344];           // bf16 pairs + zero pad
    __shared__ unsigned short offT[64];                     // byte offsets into imgp
    __shared__ float pbs[32];
    __shared__ int lastflag;

    const int b = blockIdx.x >> 3, d = blockIdx.x & 7;
    const int t = threadIdx.x;
    const int wave = t >> 6, lane = t & 63, quad = lane >> 4, l16 = lane & 15;

    // ---- imgp: packed bf16 pairs (img[y][x], img[y][x+1]), zero pad to 1344 ----
    const float* xb = x + b * 784;
    for (int j = t; j < 1344; j += 256) {
        unsigned v = 0;
        if (j < 784) {
            const float a = xb[j];
            const int xc = j - 28 * (int)(((unsigned)j * 37450u) >> 20);
            const float c = (xc < 27) ? xb[j + 1] : 0.f;
            v = (unsigned)f2bf(a) | ((unsigned)f2bf(c) << 16);
        }
        imgp[j] = v;
    }
    // ---- tap-offset tables (byte offsets, x4) ----
    if (t < 64) {
        int v;
        if (t < 32) {
            const int ky = t >> 2, kx = 2 * (t & 3);
            v = ky * 28 + kx;
        } else {
            const int k = t + 32;
            if (k < 72) {
                const int p = k >> 1, lo = k & 1, ky = p >> 2, kx = 2 * (p & 3) + lo;
                v = ky * 28 + kx;
            } else if (k < 81) {
                v = (k - 72) * 28 + 8;
            } else v = 784;
        }
        offT[t] = (unsigned short)(4 * v);
    }
    if (t < 32) pbs[t] = prim_b[t];
    if (t == 0) lastflag = 0;
    __syncthreads();

    // hoist per-lane tap byte-offsets
    unsigned tp0[4], tp1[4], t2a[4], t2b[4];
#pragma unroll
    for (int r = 0; r < 4; ++r) {
        tp0[r] = offT[quad * 4 + r];
        tp1[r] = offT[16 + quad * 4 + r];
        t2a[r] = offT[32 + quad * 8 + 2 * r];
        t2b[r] = offT[32 + quad * 8 + 2 * r + 1];
    }

    // ======== conv1: mt strided 4 across waves ========
    {
        const float cb0 = conv1_b[l16 * 8 + d];
        const float cb1 = conv1_b[(16 + l16) * 8 + d];
        bf16x8 Bw0[3], Bw1[3];
#pragma unroll
        for (int ks = 0; ks < 3; ++ks) {
            Bw0[ks] = *(const bf16x8*)&c1wp2[(l16 * 8 + d) * 96 + ks * 32 + quad * 8];
            Bw1[ks] = *(const bf16x8*)&c1wp2[((16 + l16) * 8 + d) * 96 + ks * 32 + quad * 8];
        }
        for (int mt = wave; mt < 25; mt += 4) {
            const int pos = mt * 16 + l16;
            const int y = (int)(((unsigned)pos * 52429u) >> 20);
            const unsigned pb4 = (unsigned)(pos + 8 * y) * 4u;   // 4*(y*28+x)
            f32x4 a0 = {0.f, 0.f, 0.f, 0.f}, a1 = {0.f, 0.f, 0.f, 0.f};
            union { unsigned u[4]; bf16x8 v; } A;
#pragma unroll
            for (int r = 0; r < 4; ++r)
                A.u[r] = *(const unsigned*)((const char*)imgp + (pb4 + tp0[r]));
            a0 = __builtin_amdgcn_mfma_f32_16x16x32_bf16(A.v, Bw0[0], a0, 0, 0, 0);
            a1 = __builtin_amdgcn_mfma_f32_16x16x32_bf16(A.v, Bw1[0], a1, 0, 0, 0);
#pragma unroll
            for (int r = 0; r < 4; ++r)
                A.u[r] = *(const unsigned*)((const char*)imgp + (pb4 + tp1[r]));
            a0 = __builtin_amdgcn_mfma_f32_16x16x32_bf16(A.v, Bw0[1], a0, 0, 0, 0);
            a1 = __builtin_amdgcn_mfma_f32_16x16x32_bf16(A.v, Bw1[1], a1, 0, 0, 0);
#pragma unroll
            for (int r = 0; r < 4; ++r) {
                const unsigned lo = *(const unsigned*)((const char*)imgp + (pb4 + t2a[r]));
                const unsigned hi = *(const unsigned*)((const char*)imgp + (pb4 + t2b[r]));
                A.u[r] = (lo & 0xFFFFu) | (hi << 16);
            }
            a0 = __builtin_amdgcn_mfma_f32_16x16x32_bf16(A.v, Bw0[2], a0, 0, 0, 0);
            a1 = __builtin_amdgcn_mfma_f32_16x16x32_bf16(A.v, Bw1[2], a1, 0, 0, 0);
#pragma unroll
            for (int r = 0; r < 4; ++r) {
                const int pr = mt * 16 + quad * 4 + r;
                const int spar = (int)((((unsigned)pr * 52429u) >> 21) & 1u);
                const int base = pr * 40 + 8 * spar;
                c1t[base + l16]      = f2bf(fmaxf(a0[r] + cb0, 0.f));
                c1t[base + 16 + l16] = f2bf(fmaxf(a1[r] + cb1, 0.f));
            }
        }
    }
    __syncthreads();

    // ======== prim GEMM: K=32 ch per tap, 81 taps strided 4 across waves ======
    const int hp = l16 >> 3, wp = l16 & 7;               // n = 8h' + w'
    const unsigned Lbase = 80u * (unsigned)(40 * hp + 2 * wp) + 16u * quad;
    const unsigned Lh0 = Lbase + 16u * hp;               // kk=0: spar=hp
    const unsigned Lh1 = Lbase + 16u * (1 - hp);         // kk=1: spar=1-hp

    f32x4 pa[6];
#pragma unroll
    for (int q = 0; q < 6; ++q) pa[q] = (f32x4){0.f, 0.f, 0.f, 0.f};

    {
        const unsigned short* apbase = pw2 + l16 * 32 + quad * 8;
        int off = wave;
        bf16x8 A0 = *(const bf16x8*)(apbase + off * 1024);
        bf16x8 A1 = *(const bf16x8*)(apbase + off * 1024 + 512);
        for (; off < 81; off += 4) {
            const int noff = off + 4;                    // <= 84: pw2 zero-padded
            const bf16x8 nA0 = *(const bf16x8*)(apbase + noff * 1024);
            const bf16x8 nA1 = *(const bf16x8*)(apbase + noff * 1024 + 512);
            const int ky = (off * 57) >> 9;
            const int kx = off - 9 * ky;
            const int kk = (ky >> 1) & 1;
            const unsigned soff = 80u * (unsigned)(20 * ky + kx);
            const unsigned ad = (kk ? Lh1 : Lh0) + soff;
            const char* b0 = (const char*)c1t + ad;
#pragma unroll
            for (int nt = 0; nt < 3; ++nt) {
                const bf16x8 Bf0 = *(const bf16x8*)(b0 + nt * 6400);
                pa[nt]     = __builtin_amdgcn_mfma_f32_16x16x32_bf16(A0, Bf0, pa[nt],     0, 0, 0);
                pa[3 + nt] = __builtin_amdgcn_mfma_f32_16x16x32_bf16(A1, Bf0, pa[3 + nt], 0, 0, 0);
            }
            A0 = nA0; A1 = nA1;
        }
    }
    __syncthreads();

    // ---- 4-wave tap reduction (redbuf overlays c1t) ----
    f32x4* redbuf = (f32x4*)c1t;
    if (wave >= 2) {
#pragma unroll
        for (int q = 0; q < 6; ++q) redbuf[((wave - 2) * 6 + q) * 64 + lane] = pa[q];
    }
    __syncthreads();
    if (wave < 2) {
#pragma unroll
        for (int q = 0; q < 6; ++q) pa[q] += redbuf[(wave * 6 + q) * 64 + lane];
        if (wave == 0) {               // export mt1 half
#pragma unroll
            for (int q = 0; q < 3; ++q) redbuf[(12 + q) * 64 + lane] = pa[3 + q];
        } else {                       // export mt0 half
#pragma unroll
            for (int q = 0; q < 3; ++q) redbuf[(15 + q) * 64 + lane] = pa[q];
        }
    }
    __syncthreads();

    if (wave < 2) {
        f32x4 full[3];
#pragma unroll
        for (int q = 0; q < 3; ++q)
            full[q] = (wave == 0) ? (pa[q] + redbuf[(15 + q) * 64 + lane])
                                  : (pa[3 + q] + redbuf[(12 + q) * 64 + lane]);

        // ---- ReLU + fold u * dig_W (wave = m-tile) ----
        float part[16];
#pragma unroll
        for (int k = 0; k < 16; ++k) part[k] = 0.f;

        if (wp < 6) {
#pragma unroll
            for (int nt = 0; nt < 3; ++nt) {
                const f32x4 u4 = full[nt];
                const int h = 2 * nt + hp;
#pragma unroll
                for (int r = 0; r < 4; ++r) {
                    const int o = wave * 16 + quad * 4 + r;
                    const float val = fmaxf(u4[r] + pbs[o], 0.f);
                    const int nc = o * 36 + wp * 6 + h;
                    const f32x4* wd = (const f32x4*)&dig_W[(nc * 8 + d) * 16];
#pragma unroll
                    for (int m = 0; m < 4; ++m) {
                        const f32x4 wv = wd[m];
                        part[m * 4 + 0] = fmaf(val, wv[0], part[m * 4 + 0]);
                        part[m * 4 + 1] = fmaf(val, wv[1], part[m * 4 + 1]);
                        part[m * 4 + 2] = fmaf(val, wv[2], part[m * 4 + 2]);
                        part[m * 4 + 3] = fmaf(val, wv[3], part[m * 4 + 3]);
                    }
                }
            }
        }

#pragma unroll
        for (int k = 0; k < 16; ++k) {
            float v = part[k];
            v += __shfl_xor(v, 32, 64);
            v += __shfl_xor(v, 16, 64);
            v += __shfl_xor(v, 8, 64);
            v += __shfl_xor(v, 4, 64);
            v += __shfl_xor(v, 2, 64);
            v += __shfl_xor(v, 1, 64);
            part[k] = v;
        }
        if (lane == 0) {
#pragma unroll
            for (int k = 0; k < 16; ++k) atomicAdd(&S[b * 16 + k], part[k]);
            __threadfence();           // make S-adds device-visible (release)
        }
    }
    __syncthreads();

    // ---- completion counter: last block runs the epilogue for all images ----
    if (t == 0) {
        const unsigned old = atomicAdd(done, 1u);
        lastflag = (old == (unsigned)(nblocks - 1)) ? 1 : 0;
    }
    __syncthreads();
    if (lastflag) {
        __threadfence();               // acquire: see all other blocks' S
        for (int bb = t; bb < 512; bb += 256) {
            float Sv[16]; float l2 = 0.f, l1 = 0.f;
#pragma unroll
            for (int k = 0; k < 16; ++k) {
                const float s = (S[bb * 16 + k] + colsum[k]) * (1.f / 1152.f);
                Sv[k] = s; l2 += s * s; l1 += fabsf(s);
            }
            l2 = sqrtf(l2);
            const float sc = l2 / (1.f + l2) / l1;
            float lg[10]; float mx = -1e30f;
#pragma unroll
            for (int o = 0; o < 10; ++o) {
                float a = out_b[o];
#pragma unroll
                for (int k = 0; k < 16; ++k) a = fmaf(Sv[k] * sc, OW[o * 16 + k], a);
                lg[o] = a; mx = fmaxf(mx, a);
            }
            float sum = 0.f;
#pragma unroll
            for (int o = 0; o < 10; ++o) { lg[o] = expf(lg[o] - mx); sum += lg[o]; }
            const float inv = 1.f / sum;
#pragma unroll
            for (int o = 0; o < 10; ++o) out[bb * 10 + o] = lg[o] * inv;
        }
    }
}

extern "C" void kernel_launch(void* const* d_in, const int* in_sizes, int n_in,
                              void* d_out, int out_size, void* d_ws, size_t ws_size,
                              hipStream_t stream) {
    const float* x       = (const float*)d_in[0];
    const float* conv1_w = (const float*)d_in[1];
    const float* conv1_b = (const float*)d_in[2];
    const float* prim_w  = (const float*)d_in[3];
    const float* prim_b  = (const float*)d_in[4];
    const float* dig_W   = (const float*)d_in[5];
    const float* dig_Wb  = (const float*)d_in[6];
    const float* out_w   = (const float*)d_in[7];
    const float* out_b   = (const float*)d_in[8];
    float* out = (float*)d_out;

    const int B = in_sizes[0] / 784;   // 512

    char* w = (char*)d_ws;
    float* S              = (float*)(w);                 // 32768 B
    float* colsum         = (float*)(w + 32768);         // 64 B
    float* OW             = (float*)(w + 32832);         // 640 B
    unsigned* done        = (unsigned*)(w + 33472);      // 64 B slot
    unsigned short* c1wp2 = (unsigned short*)(w + 33536);            // 49152 B
    unsigned short* pw2   = (unsigned short*)(w + 33536 + 49152);    // 174080 B

    const int nblocks = B * 8;
    caps_pre<<<469, 256, 0, stream>>>(conv1_w, prim_w, dig_Wb, out_w,
                                      S, colsum, OW, done, c1wp2, pw2, B);
    caps_main<<<nblocks, 256, 0, stream>>>(x, conv1_b, prim_b, dig_W, c1wp2, pw2,
                                           S, colsum, OW, out_b, done, out, nblocks);
}

// Round 8
// 196.583 us; speedup vs baseline: 2.1465x; 1.8719x over previous
//
#include <hip/hip_runtime.h>
#include <math.h>

// CapsNet fused forward, v8: v5 structure (2 d-slices/block, 64KB c1t,
// prefetched A-frags, 3 separate kernels, NO device fences) but with
// 512-thread blocks (8 waves): same 70KB LDS -> 2 blocks/CU -> 16 waves/CU
// (v5 had 8). launch_bounds(512,4) caps VGPR at 128 (v5 measured 124).

typedef __attribute__((ext_vector_type(8))) short bf16x8;
typedef __attribute__((ext_vector_type(4))) float f32x4;

__device__ inline unsigned short f2bf(float f) {
    union { float f; unsigned u; } v; v.f = f;
    unsigned r = v.u + 0x7fff + ((v.u >> 16) & 1);   // RNE
    return (unsigned short)(r >> 16);
}

#define C1TN 16008   // u16 per c1t slice (400*40 + 8 skew pad)

// ---------------- pre kernel ----------------
__global__ void caps_pre(const float* __restrict__ conv1_w,
                         const float* __restrict__ prim_w,
                         const float* __restrict__ dig_Wb,
                         const float* __restrict__ out_w,
                         float* __restrict__ S,              // [B*16]
                         float* __restrict__ colsum,         // [16]
                         float* __restrict__ OW,             // [160]
                         unsigned short* __restrict__ c1wp2, // [256*96]
                         unsigned short* __restrict__ pw2,   // [89*1024]
                         int B)
{
    const int t = threadIdx.x;
    if (blockIdx.x == 484) {
        __shared__ float cs[16];
        if (t < 16) cs[t] = 0.f;
        __syncthreads();
        {
            const int k = t & 15, g = t >> 4;
            float s = 0.f;
            for (int j = 0; j < 72; ++j) s += dig_Wb[(g * 72 + j) * 16 + k];
            atomicAdd(&cs[k], s);
        }
        __syncthreads();
        if (t < 16) colsum[t] = cs[t];
        if (t >= 64 && t < 224) {
            const int idx = t - 64, o = idx >> 4, k = idx & 15;
            float s = 0.f;
            for (int i = 0; i < 10; ++i) s += out_w[(o * 10 + i) * 16 + k];
            OW[idx] = s;
        }
        return;
    }
    const int tid = blockIdx.x * 256 + t;
    if (tid < 24576) {                       // c1wp2, K-permuted
        const int c = tid / 96, kn = tid % 96;
        unsigned short v = 0;
        if (kn < 72) {
            const int p = kn >> 1, lo = kn & 1, ky = p >> 2, kx = 2 * (p & 3) + lo;
            v = f2bf(conv1_w[c * 81 + 9 * ky + kx]);
        } else if (kn < 81) {
            v = f2bf(conv1_w[c * 81 + 9 * (kn - 72) + 8]);
        }
        c1wp2[tid] = v;
    } else if (tid < 107520) {               // pw2: coalesced read, scattered write
        const int j = tid - 24576;           // j = row*81 + tap, row = o*32+i
        const int row = j / 81, tap = j - 81 * row;
        pw2[tap * 1024 + row] = f2bf(prim_w[j]);
    } else if (tid < 115712) {               // zero taps 81..88 (prefetch pad)
        pw2[81 * 1024 + (tid - 107520)] = 0;
    } else {                                 // S = 0
        const int k = tid - 115712;
        if (k < B * 16) S[k] = 0.f;
    }
}

// ---------------- main kernel ----------------
__global__ __launch_bounds__(512, 4) void caps_main(
    const float* __restrict__ x,
    const float* __restrict__ conv1_b,
    const float* __restrict__ prim_b,
    const float* __restrict__ dig_W,
    const unsigned short* __restrict__ c1wp2,
    const unsigned short* __restrict__ pw2,
    float* __restrict__ S)
{
    __shared__ __align__(16) unsigned short c1t[2 * C1TN];  // 64 KB (2 d-slices)
    __shared__ __align__(16) unsigned imgp[1344];           // bf16 pairs + zero pad
    __shared__ unsigned short offT[64];                     // byte offsets into imgp
    __shared__ float pbs[32];

    const int b = blockIdx.x >> 2, dp = blockIdx.x & 3;
    const int d0 = dp * 2;
    const int t = threadIdx.x;
    const int wave = t >> 6, lane = t & 63, quad = lane >> 4, l16 = lane & 15;

    // ---- imgp: packed bf16 pairs (img[y][x], img[y][x+1]), zero pad to 1344 ----
    const float* xb = x + b * 784;
    for (int j = t; j < 1344; j += 512) {
        unsigned v = 0;
        if (j < 784) {
            const float a = xb[j];
            const int xc = j - 28 * (int)(((unsigned)j * 37450u) >> 20);
            const float c = (xc < 27) ? xb[j + 1] : 0.f;
            v = (unsigned)f2bf(a) | ((unsigned)f2bf(c) << 16);
        }
        imgp[j] = v;
    }
    // ---- tap-offset tables (byte offsets, x4) ----
    if (t < 64) {
        int v;
        if (t < 32) {
            const int ky = t >> 2, kx = 2 * (t & 3);
            v = ky * 28 + kx;
        } else {
            const int k = t + 32;
            if (k < 72) {
                const int p = k >> 1, lo = k & 1, ky = p >> 2, kx = 2 * (p & 3) + lo;
                v = ky * 28 + kx;
            } else if (k < 81) {
                v = (k - 72) * 28 + 8;
            } else v = 784;
        }
        offT[t] = (unsigned short)(4 * v);
    }
    if (t < 32) pbs[t] = prim_b[t];
    __syncthreads();

    // hoist per-lane tap byte-offsets
    unsigned tp0[4], tp1[4], t2a[4], t2b[4];
#pragma unroll
    for (int r = 0; r < 4; ++r) {
        tp0[r] = offT[quad * 4 + r];
        tp1[r] = offT[16 + quad * 4 + r];
        t2a[r] = offT[32 + quad * 8 + 2 * r];
        t2b[r] = offT[32 + quad * 8 + 2 * r + 1];
    }

    // ======== conv1: waves 0-3 -> e=0; waves 4-7 -> e=1; mt strided 4 ========
    {
        const int e = wave >> 2;
        const int d = d0 + e;
        unsigned short* dst = c1t + e * C1TN;
        const float cb0 = conv1_b[l16 * 8 + d];
        const float cb1 = conv1_b[(16 + l16) * 8 + d];
        bf16x8 Bw0[3], Bw1[3];
#pragma unroll
        for (int ks = 0; ks < 3; ++ks) {
            Bw0[ks] = *(const bf16x8*)&c1wp2[(l16 * 8 + d) * 96 + ks * 32 + quad * 8];
            Bw1[ks] = *(const bf16x8*)&c1wp2[((16 + l16) * 8 + d) * 96 + ks * 32 + quad * 8];
        }
        for (int mt = (wave & 3); mt < 25; mt += 4) {
            const int pos = mt * 16 + l16;
            const int y = (int)(((unsigned)pos * 52429u) >> 20);
            const unsigned pb4 = (unsigned)(pos + 8 * y) * 4u;   // 4*(y*28+x)
            f32x4 a0 = {0.f, 0.f, 0.f, 0.f}, a1 = {0.f, 0.f, 0.f, 0.f};
            union { unsigned u[4]; bf16x8 v; } A;
#pragma unroll
            for (int r = 0; r < 4; ++r)
                A.u[r] = *(const unsigned*)((const char*)imgp + (pb4 + tp0[r]));
            a0 = __builtin_amdgcn_mfma_f32_16x16x32_bf16(A.v, Bw0[0], a0, 0, 0, 0);
            a1 = __builtin_amdgcn_mfma_f32_16x16x32_bf16(A.v, Bw1[0], a1, 0, 0, 0);
#pragma unroll
            for (int r = 0; r < 4; ++r)
                A.u[r] = *(const unsigned*)((const char*)imgp + (pb4 + tp1[r]));
            a0 = __builtin_amdgcn_mfma_f32_16x16x32_bf16(A.v, Bw0[1], a0, 0, 0, 0);
            a1 = __builtin_amdgcn_mfma_f32_16x16x32_bf16(A.v, Bw1[1], a1, 0, 0, 0);
#pragma unroll
            for (int r = 0; r < 4; ++r) {
                const unsigned lo = *(const unsigned*)((const char*)imgp + (pb4 + t2a[r]));
                const unsigned hi = *(const unsigned*)((const char*)imgp + (pb4 + t2b[r]));
                A.u[r] = (lo & 0xFFFFu) | (hi << 16);
            }
            a0 = __builtin_amdgcn_mfma_f32_16x16x32_bf16(A.v, Bw0[2], a0, 0, 0, 0);
            a1 = __builtin_amdgcn_mfma_f32_16x16x32_bf16(A.v, Bw1[2], a1, 0, 0, 0);
#pragma unroll
            for (int r = 0; r < 4; ++r) {
                const int pr = mt * 16 + quad * 4 + r;
                const int spar = (int)((((unsigned)pr * 52429u) >> 21) & 1u);
                const int base = pr * 40 + 8 * spar;
                dst[base + l16]      = f2bf(fmaxf(a0[r] + cb0, 0.f));
                dst[base + 16 + l16] = f2bf(fmaxf(a1[r] + cb1, 0.f));
            }
        }
    }
    __syncthreads();

    // ======== prim GEMM: K=32 ch per tap, 81 taps strided 8 across waves =====
    const int hp = l16 >> 3, wp = l16 & 7;               // n = 8h' + w'
    const unsigned Lbase = 80u * (unsigned)(40 * hp + 2 * wp) + 16u * quad;
    const unsigned Lh0 = Lbase + 16u * hp;               // kk=0: spar=hp
    const unsigned Lh1 = Lbase + 16u * (1 - hp);         // kk=1: spar=1-hp

    f32x4 pa[12];
#pragma unroll
    for (int q = 0; q < 12; ++q) pa[q] = (f32x4){0.f, 0.f, 0.f, 0.f};

    {
        const unsigned short* apbase = pw2 + l16 * 32 + quad * 8;
        int off = wave;
        bf16x8 A0 = *(const bf16x8*)(apbase + off * 1024);
        bf16x8 A1 = *(const bf16x8*)(apbase + off * 1024 + 512);
        for (; off < 81; off += 8) {
            const int noff = off + 8;                    // <= 88: pw2 zero-padded
            const bf16x8 nA0 = *(const bf16x8*)(apbase + noff * 1024);
            const bf16x8 nA1 = *(const bf16x8*)(apbase + noff * 1024 + 512);
            const int ky = (off * 57) >> 9;
            const int kx = off - 9 * ky;
            const int kk = (ky >> 1) & 1;
            const unsigned soff = 80u * (unsigned)(20 * ky + kx);
            const unsigned ad = (kk ? Lh1 : Lh0) + soff;
            const char* b0 = (const char*)c1t + ad;
#pragma unroll
            for (int nt = 0; nt < 3; ++nt) {
                const bf16x8 Bf0 = *(const bf16x8*)(b0 + nt * 6400);
                const bf16x8 Bf1 = *(const bf16x8*)(b0 + nt * 6400 + 2 * C1TN);
                pa[nt]     = __builtin_amdgcn_mfma_f32_16x16x32_bf16(A0, Bf0, pa[nt],     0, 0, 0);
                pa[3 + nt] = __builtin_amdgcn_mfma_f32_16x16x32_bf16(A1, Bf0, pa[3 + nt], 0, 0, 0);
                pa[6 + nt] = __builtin_amdgcn_mfma_f32_16x16x32_bf16(A0, Bf1, pa[6 + nt], 0, 0, 0);
                pa[9 + nt] = __builtin_amdgcn_mfma_f32_16x16x32_bf16(A1, Bf1, pa[9 + nt], 0, 0, 0);
            }
            A0 = nA0; A1 = nA1;
        }
    }
    __syncthreads();

    // ---- 8-wave tap reduction (redbuf overlays c1t) ----
    f32x4* redbuf = (f32x4*)c1t;
    if (wave >= 4) {        // stage 1: waves 4-7 export
#pragma unroll
        for (int q = 0; q < 12; ++q) redbuf[((wave - 4) * 12 + q) * 64 + lane] = pa[q];
    }
    __syncthreads();
    if (wave < 4) {
#pragma unroll
        for (int q = 0; q < 12; ++q) pa[q] += redbuf[(wave * 12 + q) * 64 + lane];
    }
    __syncthreads();
    if (wave == 2 || wave == 3) {   // stage 2: waves 2,3 export
#pragma unroll
        for (int q = 0; q < 12; ++q) redbuf[((wave - 2) * 12 + q) * 64 + lane] = pa[q];
    }
    __syncthreads();
    if (wave < 2) {
#pragma unroll
        for (int q = 0; q < 12; ++q) pa[q] += redbuf[(wave * 12 + q) * 64 + lane];
        // stage 3: cross-exchange halves (rows 24..35, untouched since stage 1)
        if (wave == 0) {
#pragma unroll
            for (int q = 0; q < 6; ++q) redbuf[(24 + q) * 64 + lane] = pa[6 + q];
        } else {
#pragma unroll
            for (int q = 0; q < 6; ++q) redbuf[(30 + q) * 64 + lane] = pa[q];
        }
    }
    __syncthreads();

    if (wave < 2) {
        const int d = d0 + wave;
        f32x4 full[6];
#pragma unroll
        for (int q = 0; q < 6; ++q)
            full[q] = (wave == 0) ? (pa[q] + redbuf[(30 + q) * 64 + lane])
                                  : (pa[6 + q] + redbuf[(24 + q) * 64 + lane]);

        // ---- ReLU + fold u * dig_W ----
        float part[16];
#pragma unroll
        for (int k = 0; k < 16; ++k) part[k] = 0.f;

        if (wp < 6) {
#pragma unroll
            for (int mt = 0; mt < 2; ++mt)
#pragma unroll
                for (int nt = 0; nt < 3; ++nt) {
                    const f32x4 u4 = full[mt * 3 + nt];
                    const int h = 2 * nt + hp;
#pragma unroll
                    for (int r = 0; r < 4; ++r) {
                        const int o = mt * 16 + quad * 4 + r;
                        const float val = fmaxf(u4[r] + pbs[o], 0.f);
                        const int nc = o * 36 + wp * 6 + h;
                        const f32x4* wd = (const f32x4*)&dig_W[(nc * 8 + d) * 16];
#pragma unroll
                        for (int m = 0; m < 4; ++m) {
                            const f32x4 wv = wd[m];
                            part[m * 4 + 0] = fmaf(val, wv[0], part[m * 4 + 0]);
                            part[m * 4 + 1] = fmaf(val, wv[1], part[m * 4 + 1]);
                            part[m * 4 + 2] = fmaf(val, wv[2], part[m * 4 + 2]);
                            part[m * 4 + 3] = fmaf(val, wv[3], part[m * 4 + 3]);
                        }
                    }
                }
        }

#pragma unroll
        for (int k = 0; k < 16; ++k) {
            float v = part[k];
            v += __shfl_xor(v, 32, 64);
            v += __shfl_xor(v, 16, 64);
            v += __shfl_xor(v, 8, 64);
            v += __shfl_xor(v, 4, 64);
            v += __shfl_xor(v, 2, 64);
            v += __shfl_xor(v, 1, 64);
            part[k] = v;
        }
        if (lane == 0) {
#pragma unroll
            for (int k = 0; k < 16; ++k) atomicAdd(&S[b * 16 + k], part[k]);
        }
    }
}

// ---------------- epilogue kernel ----------------
__global__ void caps_epi(const float* __restrict__ S, const float* __restrict__ colsum,
                         const float* __restrict__ OW, const float* __restrict__ out_b,
                         float* __restrict__ out, int B)
{
    const int b = blockIdx.x * 256 + threadIdx.x;
    if (b >= B) return;
    float Sv[16]; float l2 = 0.f, l1 = 0.f;
#pragma unroll
    for (int k = 0; k < 16; ++k) {
        const float s = (S[b * 16 + k] + colsum[k]) * (1.f / 1152.f);
        Sv[k] = s; l2 += s * s; l1 += fabsf(s);
    }
    l2 = sqrtf(l2);
    const float sc = l2 / (1.f + l2) / l1;
    float lg[10]; float mx = -1e30f;
#pragma unroll
    for (int o = 0; o < 10; ++o) {
        float a = out_b[o];
#pragma unroll
        for (int k = 0; k < 16; ++k) a = fmaf(Sv[k] * sc, OW[o * 16 + k], a);
        lg[o] = a; mx = fmaxf(mx, a);
    }
    float sum = 0.f;
#pragma unroll
    for (int o = 0; o < 10; ++o) { lg[o] = expf(lg[o] - mx); sum += lg[o]; }
    const float inv = 1.f / sum;
#pragma unroll
    for (int o = 0; o < 10; ++o) out[b * 10 + o] = lg[o] * inv;
}

extern "C" void kernel_launch(void* const* d_in, const int* in_sizes, int n_in,
                              void* d_out, int out_size, void* d_ws, size_t ws_size,
                              hipStream_t stream) {
    const float* x       = (const float*)d_in[0];
    const float* conv1_w = (const float*)d_in[1];
    const float* conv1_b = (const float*)d_in[2];
    const float* prim_w  = (const float*)d_in[3];
    const float* prim_b  = (const float*)d_in[4];
    const float* dig_W   = (const float*)d_in[5];
    const float* dig_Wb  = (const float*)d_in[6];
    const float* out_w   = (const float*)d_in[7];
    const float* out_b   = (const float*)d_in[8];
    float* out = (float*)d_out;

    const int B = in_sizes[0] / 784;   // 512

    char* w = (char*)d_ws;
    float* S              = (float*)(w);                 // 32768 B
    float* colsum         = (float*)(w + 32768);         // 64 B
    float* OW             = (float*)(w + 32832);         // 640 B
    unsigned short* c1wp2 = (unsigned short*)(w + 33536);            // 49152 B
    unsigned short* pw2   = (unsigned short*)(w + 33536 + 49152);    // 89*1024*2 B

    caps_pre<<<485, 256, 0, stream>>>(conv1_w, prim_w, dig_Wb, out_w,
                                      S, colsum, OW, c1wp2, pw2, B);
    caps_main<<<B * 4, 512, 0, stream>>>(x, conv1_b, prim_b, dig_W, c1wp2, pw2, S);
    caps_epi<<<(B + 255) / 256, 256, 0, stream>>>(S, colsum, OW, out_b, out, B);
}